// Round 9
// baseline (698.458 us; speedup 1.0000x reference)
//
#include <hip/hip_runtime.h>
#include <stdint.h>

// OHEM MSE loss, exact selection. Key facts:
//  - loss = (p-t)^2 / 2^23; selection order == raw (p-t)^2 float-bit order
//    (scaling by exact power of 2 is monotone; threshold is deep in normal
//    range so bit compare on RAW sq is exact for the mask).
//  - sum: reference computes f32(w*sq)/2^23; we accumulate f32(w*sq) in f64
//    and scale once at the end (exact, same single f32 rounding).
// Pipeline: sample-hist (4 MB) -> bin window (bl,bh] with 5-sigma margin ->
// ONE full 201 MB pass (sum/count above bh, compact window elems) -> exact
// bracket check (fallback mode2 if sampling lied / ws too small) -> finish
// selection on ~200k candidates with tiny kernels.

#define BIN_SHIFT 17
#define NBINS 32768
#define NB_WORDS (NBINS / 2)
#define WMAX 4096
#define H2_SIZE 131072
#define SHARDS 64

// ws layout (bytes):
#define OFF_WIN   131072u   // u32 winhist[4096]
#define OFF_H2    147456u   // u32 hist2[131072]
#define OFF_FULL  671744u   // u32 fullhist[32768]  (mode2 only)
#define OFF_META  802816u   // u32 meta[32]
#define OFF_SUMS  802944u   // double sums[4]
#define OFF_SHC   802976u   // u32 shard_cnt[64]
#define OFF_CAND  803232u   // uint2 cand[SHARDS][cap]
// meta: 0=bl(int) 1=bh 2=mode 3=overflow 4=cntA 5=candTot 6=b 7=k3 8=thr
//       9=cntSel 11=k2

__device__ __forceinline__ void hist_add4(uint32_t* lh, float4 pv, float4 tv) {
    float d0 = pv.x - tv.x, d1 = pv.y - tv.y, d2 = pv.z - tv.z, d3 = pv.w - tv.w;
    uint32_t b0 = __float_as_uint(d0 * d0) >> BIN_SHIFT;
    uint32_t b1 = __float_as_uint(d1 * d1) >> BIN_SHIFT;
    uint32_t b2 = __float_as_uint(d2 * d2) >> BIN_SHIFT;
    uint32_t b3 = __float_as_uint(d3 * d3) >> BIN_SHIFT;
    atomicAdd(&lh[b0 >> 1], 1u << ((b0 & 1) * 16));
    atomicAdd(&lh[b1 >> 1], 1u << ((b1 & 1) * 16));
    atomicAdd(&lh[b2 >> 1], 1u << ((b2 & 1) * 16));
    atomicAdd(&lh[b3 >> 1], 1u << ((b3 & 1) * 16));
}

// Sample pass: 512 chunks of 64 consecutive float4 (1 KB), 1/128 of elems.
// 64 blocks x 256 thr; LDS u16-packed hist (per-block count 2048 << 65535).
__global__ __launch_bounds__(256) void k_sample(
    const float4* __restrict__ p, const float4* __restrict__ t,
    uint32_t* __restrict__ shist, int n4, int chunk_stride)
{
    __shared__ uint32_t lh[NB_WORDS];
    for (int j = threadIdx.x; j < NB_WORDS; j += 256) lh[j] = 0;
    __syncthreads();
    const int gw = blockIdx.x * 4 + (threadIdx.x >> 6);
    const int lane = threadIdx.x & 63;
    #pragma unroll
    for (int c = 0; c < 2; c++) {
        int ch = gw * 2 + c;
        int idx = ch * chunk_stride + lane;
        if (idx < n4) hist_add4(lh, p[idx], t[idx]);
    }
    __syncthreads();
    for (int j = threadIdx.x; j < NB_WORDS; j += 256) {
        uint32_t v = lh[j];
        uint32_t c0 = v & 0xFFFFu, c1 = v >> 16;
        if (c0) atomicAdd(&shist[2 * j], c0);
        if (c1) atomicAdd(&shist[2 * j + 1], c1);
    }
}

// Pick bin window (bl, bh] bracketing the k-th largest, from the sample hist.
__global__ __launch_bounds__(1024) void k_bounds(
    const uint32_t* __restrict__ shist, const int* __restrict__ mk,
    uint32_t* __restrict__ meta, uint32_t inv)
{
    __shared__ uint32_t psum[1024];
    __shared__ uint32_t gsuf[64];
    __shared__ uint32_t sBh, sBlp1;
    const int t = threadIdx.x;
    if (t == 0) { sBh = 0xFFFFFFFFu; sBlp1 = 0u; }
    const int per = NBINS / 1024;                     // 32
    const int base = t * per;
    uint32_t s = 0;
    for (int i = 0; i < per; i++) s += shist[base + i];
    psum[t] = s;
    __syncthreads();
    if (t < 64) {
        uint32_t g = 0;
        for (int i = 0; i < 16; i++) g += psum[t * 16 + i];
        uint32_t v = g;
        #pragma unroll
        for (int off = 1; off < 64; off <<= 1) {
            uint32_t o = __shfl_down(v, off);
            if (t + off < 64) v += o;
        }
        gsuf[t] = v;
    }
    __syncthreads();
    const int g = t >> 4;
    uint32_t cum = (g < 63) ? gsuf[g + 1] : 0;
    const int gend = g * 16 + 15;
    for (int j = t + 1; j <= gend; j++) cum += psum[j];

    const uint32_t k = (uint32_t)(*mk);
    const uint32_t M = k / 25 + inv;                  // ~4% margin (~5 sigma)
    const uint32_t A = (k > M) ? (k - M) / inv : 0u;
    const uint32_t B = (k + M + inv - 1) / inv;
    uint32_t srun = cum;                              // S(j): samples in bins > j
    uint32_t lminBh = 0xFFFFFFFFu, lmaxBl = 0u;
    for (int i = per - 1; i >= 0; i--) {
        uint32_t j = (uint32_t)(base + i);
        if (srun <= A) lminBh = j;                    // keep smallest qualifying j
        if (srun >= B && lmaxBl == 0u) lmaxBl = j + 1; // first hit = largest j
        srun += shist[base + i];
    }
    if (lminBh != 0xFFFFFFFFu) atomicMin(&sBh, lminBh);
    if (lmaxBl) atomicMax(&sBlp1, lmaxBl);
    __syncthreads();
    if (t == 0) {
        int bh = (sBh == 0xFFFFFFFFu) ? (NBINS - 1) : (int)sBh;
        int bl = (int)sBlp1 - 1;
        if (bl >= bh) bl = bh - 1;
        if (bh - bl > WMAX) bl = bh - WMAX;           // bracket check validates
        meta[0] = (uint32_t)bl;
        meta[1] = (uint32_t)bh;
    }
}

// THE one full pass (201 MB): exact sum/count of bin>bh; compact bin in
// (bl,bh] to sharded candidate lists. R2-proven loop shape (unroll-2
// grid-stride, low VGPR); no histograms, no flush.
__global__ __launch_bounds__(256) void k_main(
    const float4* __restrict__ p, const float4* __restrict__ t,
    const float4* __restrict__ w, uint32_t* __restrict__ meta,
    double* __restrict__ sums, uint32_t* __restrict__ shard_cnt,
    uint2* __restrict__ cand, uint32_t cap, int n4)
{
    const int bl = (int)meta[0];
    const int bh = (int)meta[1];
    double lsum = 0.0;
    uint32_t lcnt = 0;
    const int lane = threadIdx.x & 63;
    const int shard = blockIdx.x & (SHARDS - 1);
    uint32_t* my_cnt = &shard_cnt[shard];
    uint2* my_cand = cand + (size_t)shard * cap;

    auto proc = [&](float4 pv, float4 tv, float4 wv) {
        float d0 = pv.x - tv.x, d1 = pv.y - tv.y, d2 = pv.z - tv.z, d3 = pv.w - tv.w;
        float s0 = d0 * d0, s1 = d1 * d1, s2 = d2 * d2, s3 = d3 * d3;
        uint32_t q0 = __float_as_uint(s0), q1 = __float_as_uint(s1);
        uint32_t q2 = __float_as_uint(s2), q3 = __float_as_uint(s3);
        int e0 = (int)(q0 >> BIN_SHIFT), e1 = (int)(q1 >> BIN_SHIFT);
        int e2 = (int)(q2 >> BIN_SHIFT), e3 = (int)(q3 >> BIN_SHIFT);
        bool a0 = e0 > bh, a1 = e1 > bh, a2 = e2 > bh, a3 = e3 > bh;
        lcnt += (a0 ? 1u : 0u) + (a1 ? 1u : 0u) + (a2 ? 1u : 0u) + (a3 ? 1u : 0u);
        lsum += a0 ? (double)(wv.x * s0) : 0.0;
        lsum += a1 ? (double)(wv.y * s1) : 0.0;
        lsum += a2 ? (double)(wv.z * s2) : 0.0;
        lsum += a3 ? (double)(wv.w * s3) : 0.0;
        bool c0 = (!a0) && (e0 > bl), c1 = (!a1) && (e1 > bl);
        bool c2 = (!a2) && (e2 > bl), c3 = (!a3) && (e3 > bl);
        if (__ballot(c0 | c1 | c2 | c3)) {            // rare (~1.5% of f4s)
            uint32_t qs[4] = {q0, q1, q2, q3};
            float wws[4] = {wv.x, wv.y, wv.z, wv.w};
            bool cs[4] = {c0, c1, c2, c3};
            #pragma unroll
            for (int c = 0; c < 4; c++) {
                unsigned long long m = __ballot(cs[c]);
                if (m) {
                    int leader = __ffsll((unsigned long long)m) - 1;
                    uint32_t base_ = 0;
                    if (lane == leader)
                        base_ = atomicAdd(my_cnt, (uint32_t)__popcll(m));
                    base_ = __shfl(base_, leader);
                    if (cs[c]) {
                        uint32_t idx = base_ +
                            (uint32_t)__popcll(m & ((1ull << lane) - 1ull));
                        if (idx < cap)
                            my_cand[idx] = make_uint2(qs[c], __float_as_uint(wws[c]));
                        else
                            meta[3] = 1u;             // overflow -> mode2
                    }
                }
            }
        }
    };

    const int S = gridDim.x * 256;
    int i = blockIdx.x * 256 + threadIdx.x;
    for (; i + S < n4; i += 2 * S) {
        float4 pv0 = p[i],     tv0 = t[i],     wv0 = w[i];
        float4 pv1 = p[i + S], tv1 = t[i + S], wv1 = w[i + S];
        proc(pv0, tv0, wv0);
        proc(pv1, tv1, wv1);
    }
    for (; i < n4; i += S) proc(p[i], t[i], w[i]);

    #pragma unroll
    for (int off = 32; off; off >>= 1) {
        lsum += __shfl_down(lsum, off);
        lcnt += __shfl_down(lcnt, off);
    }
    __shared__ double sred[4];
    __shared__ uint32_t cred[4];
    const int wid = threadIdx.x >> 6;
    if (lane == 0) { sred[wid] = lsum; cred[wid] = lcnt; }
    __syncthreads();
    if (threadIdx.x == 0) {
        atomicAdd(&sums[0], sred[0] + sred[1] + sred[2] + sred[3]);
        atomicAdd(&meta[4], cred[0] + cred[1] + cred[2] + cred[3]);
    }
}

// Exact bracket check: decides fast path (mode0) vs full fallback (mode2).
__global__ __launch_bounds__(64) void k_check(
    const uint32_t* __restrict__ shc, const int* __restrict__ mk,
    uint32_t* __restrict__ meta)
{
    uint32_t c = shc[threadIdx.x];
    #pragma unroll
    for (int off = 32; off; off >>= 1) c += __shfl_down(c, off);
    if (threadIdx.x == 0) {
        uint32_t k = (uint32_t)(*mk);
        uint32_t cntA = meta[4];
        int bl = (int)meta[0], bh = (int)meta[1];
        uint32_t W = (uint32_t)(bh - bl);
        bool ok = (meta[3] == 0u) && (cntA < k) && (k <= cntA + c) &&
                  (W >= 1u) && (W <= (uint32_t)WMAX);
        meta[2] = ok ? 0u : 2u;
        meta[5] = c;
        meta[11] = ok ? (k - cntA) : 0u;
    }
}

// Per-window-bin counts (fast: candidates; slow: full-data 15-bit hist).
__global__ __launch_bounds__(256) void k_winhist(
    const float4* __restrict__ p, const float4* __restrict__ t,
    const uint32_t* __restrict__ shc, const uint2* __restrict__ cand,
    uint32_t cap, uint32_t* __restrict__ meta,
    uint32_t* __restrict__ winhist, uint32_t* __restrict__ fullhist, int n4)
{
    if (meta[2] == 0u) {
        __shared__ uint32_t lw[WMAX];
        for (int j = threadIdx.x; j < WMAX; j += 256) lw[j] = 0;
        __syncthreads();
        const int bl = (int)meta[0];
        const int s = blockIdx.x;
        if (s < SHARDS) {
            uint32_t cnt = shc[s]; if (cnt > cap) cnt = cap;
            const uint2* cs = cand + (size_t)s * cap;
            for (uint32_t i = threadIdx.x; i < cnt; i += 256) {
                int wi = (int)(cs[i].x >> BIN_SHIFT) - bl - 1;
                atomicAdd(&lw[wi], 1u);
            }
        }
        __syncthreads();
        for (int j = threadIdx.x; j < WMAX; j += 256)
            if (lw[j]) atomicAdd(&winhist[j], lw[j]);
    } else {
        const int S = gridDim.x * 256;
        for (int i = blockIdx.x * 256 + threadIdx.x; i < n4; i += S) {
            float4 pv = p[i], tv = t[i];
            float d[4] = {pv.x - tv.x, pv.y - tv.y, pv.z - tv.z, pv.w - tv.w};
            #pragma unroll
            for (int c = 0; c < 4; c++)
                atomicAdd(&fullhist[__float_as_uint(d[c] * d[c]) >> BIN_SHIFT], 1u);
        }
    }
}

// Generic suffix (from-top) rank select over u32 hist; 1024 threads.
__device__ void suffix_select(const uint32_t* __restrict__ h, int per,
                              uint32_t r, uint32_t* out2)
{
    __shared__ uint32_t psum[1024];
    __shared__ uint32_t gsuf[64];
    const int t = threadIdx.x;
    if (t == 0) { out2[0] = 0u; out2[1] = 1u; }
    const int base = t * per;
    uint32_t s = 0;
    for (int i = 0; i < per; i++) s += h[base + i];
    psum[t] = s;
    __syncthreads();
    if (t < 64) {
        uint32_t g = 0;
        for (int i = 0; i < 16; i++) g += psum[t * 16 + i];
        uint32_t v = g;
        #pragma unroll
        for (int off = 1; off < 64; off <<= 1) {
            uint32_t o = __shfl_down(v, off);
            if (t + off < 64) v += o;
        }
        gsuf[t] = v;
    }
    __syncthreads();
    const int g = t >> 4;
    uint32_t cum = (g < 63) ? gsuf[g + 1] : 0;
    const int gend = g * 16 + 15;
    for (int j = t + 1; j <= gend; j++) cum += psum[j];
    if (cum < r && r <= cum + psum[t]) {
        uint32_t c = cum;
        for (int i = per - 1; i >= 0; i--) {
            uint32_t hh = h[base + i];
            c += hh;
            if (c >= r) {
                out2[0] = (uint32_t)(base + i);
                out2[1] = r - (c - hh);
                break;
            }
        }
    }
    __syncthreads();
}

__global__ __launch_bounds__(1024) void k2_scan(
    const uint32_t* __restrict__ winhist, const uint32_t* __restrict__ fullhist,
    const int* __restrict__ mk, uint32_t* __restrict__ meta)
{
    __shared__ uint32_t out2[2];
    const uint32_t mode = meta[2];
    const uint32_t* src = mode ? fullhist : winhist;
    const int per = mode ? (NBINS / 1024) : (WMAX / 1024);
    const uint32_t r = mode ? (uint32_t)(*mk) : meta[11];
    suffix_select(src, per, r, out2);
    if (threadIdx.x == 0) {
        uint32_t b = mode ? out2[0]
                          : (uint32_t)((int)meta[0] + 1 + (int)out2[0]);
        meta[6] = b;
        meta[7] = out2[1];
    }
}

__global__ __launch_bounds__(256) void k3_hist(
    const float4* __restrict__ p, const float4* __restrict__ t,
    const uint32_t* __restrict__ shc, const uint2* __restrict__ cand,
    uint32_t cap, uint32_t* __restrict__ meta, uint32_t* __restrict__ hist2,
    int n4)
{
    const uint32_t b = meta[6];
    if (meta[2] == 0u) {
        const int s = blockIdx.x;
        if (s >= SHARDS) return;
        uint32_t cnt = shc[s]; if (cnt > cap) cnt = cap;
        const uint2* cs = cand + (size_t)s * cap;
        for (uint32_t i = threadIdx.x; i < cnt; i += 256) {
            uint32_t q = cs[i].x;
            if ((q >> BIN_SHIFT) == b) atomicAdd(&hist2[q & (H2_SIZE - 1)], 1u);
        }
    } else {
        const int S = gridDim.x * 256;
        for (int i = blockIdx.x * 256 + threadIdx.x; i < n4; i += S) {
            float4 pv = p[i], tv = t[i];
            float d[4] = {pv.x - tv.x, pv.y - tv.y, pv.z - tv.z, pv.w - tv.w};
            #pragma unroll
            for (int c = 0; c < 4; c++) {
                uint32_t q = __float_as_uint(d[c] * d[c]);
                if ((q >> BIN_SHIFT) == b) atomicAdd(&hist2[q & (H2_SIZE - 1)], 1u);
            }
        }
    }
}

__global__ __launch_bounds__(1024) void k3_scan(
    const uint32_t* __restrict__ hist2, uint32_t* __restrict__ meta)
{
    __shared__ uint32_t out2[2];
    suffix_select(hist2, H2_SIZE / 1024, meta[7], out2);
    if (threadIdx.x == 0)
        meta[8] = (meta[6] << BIN_SHIFT) | out2[0];
}

__global__ __launch_bounds__(256) void k4_sum(
    const float4* __restrict__ p, const float4* __restrict__ t,
    const float4* __restrict__ w, const uint32_t* __restrict__ shc,
    const uint2* __restrict__ cand, uint32_t cap,
    uint32_t* __restrict__ meta, double* __restrict__ sums, int n4)
{
    const uint32_t thr = meta[8];
    double lsum = 0.0;
    uint32_t lcnt = 0;
    if (meta[2] == 0u) {
        const int s = blockIdx.x & (SHARDS - 1);
        uint32_t cnt = shc[s]; if (cnt > cap) cnt = cap;
        const uint2* cs = cand + (size_t)s * cap;
        for (uint32_t i = (blockIdx.x >> 6) * 256 + threadIdx.x; i < cnt;
             i += (gridDim.x >> 6) * 256) {
            uint2 e = cs[i];
            if (e.x > thr) {
                lcnt++;
                lsum += (double)(__uint_as_float(e.y) * __uint_as_float(e.x));
            }
        }
    } else {
        const int S = gridDim.x * 256;
        for (int i = blockIdx.x * 256 + threadIdx.x; i < n4; i += S) {
            float4 pv = p[i], tv = t[i], wv = w[i];
            float d[4] = {pv.x - tv.x, pv.y - tv.y, pv.z - tv.z, pv.w - tv.w};
            float wa[4] = {wv.x, wv.y, wv.z, wv.w};
            #pragma unroll
            for (int c = 0; c < 4; c++) {
                float sq = d[c] * d[c];
                if (__float_as_uint(sq) > thr) {
                    lcnt++;
                    lsum += (double)(wa[c] * sq);
                }
            }
        }
    }
    #pragma unroll
    for (int off = 32; off; off >>= 1) {
        lsum += __shfl_down(lsum, off);
        lcnt += __shfl_down(lcnt, off);
    }
    __shared__ double sred[4];
    __shared__ uint32_t cred[4];
    const int wid = threadIdx.x >> 6, lane = threadIdx.x & 63;
    if (lane == 0) { sred[wid] = lsum; cred[wid] = lcnt; }
    __syncthreads();
    if (threadIdx.x == 0) {
        atomicAdd(&sums[1], sred[0] + sred[1] + sred[2] + sred[3]);
        atomicAdd(&meta[9], cred[0] + cred[1] + cred[2] + cred[3]);
    }
}

__global__ __launch_bounds__(64) void k_final(
    const double* __restrict__ sums, const uint32_t* __restrict__ meta,
    float* __restrict__ out)
{
    if (threadIdx.x == 0 && blockIdx.x == 0) {
        double s, c;
        if (meta[2] == 0u) {
            s = sums[0] + sums[1];
            c = (double)(meta[4] + meta[9]);
        } else {
            s = sums[1];
            c = (double)meta[9];
        }
        out[0] = (float)((s * 0x1p-23) / c);
    }
}

extern "C" void kernel_launch(void* const* d_in, const int* in_sizes, int n_in,
                              void* d_out, int out_size, void* d_ws, size_t ws_size,
                              hipStream_t stream) {
    const float4* p = (const float4*)d_in[0];
    const float4* t = (const float4*)d_in[1];
    const float4* w = (const float4*)d_in[2];
    const int* mk = (const int*)d_in[3];
    float* out = (float*)d_out;
    const int n = in_sizes[0];           // 16777216
    const int n4 = n / 4;

    uint8_t* ws = (uint8_t*)d_ws;
    uint32_t* shist    = (uint32_t*)ws;
    uint32_t* winhist  = (uint32_t*)(ws + OFF_WIN);
    uint32_t* hist2    = (uint32_t*)(ws + OFF_H2);
    uint32_t* fullhist = (uint32_t*)(ws + OFF_FULL);
    uint32_t* meta     = (uint32_t*)(ws + OFF_META);
    double*   sums     = (double*)(ws + OFF_SUMS);
    uint32_t* shc      = (uint32_t*)(ws + OFF_SHC);
    uint2*    cand     = (uint2*)(ws + OFF_CAND);
    uint32_t cap = 0;
    if (ws_size > OFF_CAND + 8ull * SHARDS)
        cap = (uint32_t)((ws_size - OFF_CAND) / (8ull * SHARDS));

    int chunk_stride = n4 / 512; if (chunk_stride < 1) chunk_stride = 1;
    uint32_t inv = (uint32_t)(n / 131072); if (inv < 1) inv = 1;

    hipMemsetAsync(d_ws, 0, OFF_CAND, stream);
    k_sample<<<64, 256, 0, stream>>>(p, t, shist, n4, chunk_stride);
    k_bounds<<<1, 1024, 0, stream>>>(shist, mk, meta, inv);
    k_main<<<4096, 256, 0, stream>>>(p, t, w, meta, sums, shc, cand, cap, n4);
    k_check<<<1, 64, 0, stream>>>(shc, mk, meta);
    k_winhist<<<64, 256, 0, stream>>>(p, t, shc, cand, cap, meta, winhist,
                                      fullhist, n4);
    k2_scan<<<1, 1024, 0, stream>>>(winhist, fullhist, mk, meta);
    k3_hist<<<64, 256, 0, stream>>>(p, t, shc, cand, cap, meta, hist2, n4);
    k3_scan<<<1, 1024, 0, stream>>>(hist2, meta);
    k4_sum<<<256, 256, 0, stream>>>(p, t, w, shc, cand, cap, meta, sums, n4);
    k_final<<<1, 64, 0, stream>>>(sums, meta, out);
}